// Round 11
// baseline (249.575 us; speedup 1.0000x reference)
//
#include <hip/hip_runtime.h>
#include <cstdint>

#define CAP 32768    // slots per bucket (expected fill ~16.3k)
#define CHUNK 2048   // edges per scatter block

typedef __attribute__((ext_vector_type(8))) short bf8_t;   // 8 bf16 = 4 VGPRs
typedef __attribute__((ext_vector_type(4))) float f4_t;

// ---------------------------------------------------------------------------
// bf16 helpers (manual integer RNE).
// R7 lesson: v_cvt_pk_bf16_f32 inline-asm FAILED refcheck (absmax 0.0244 vs
// 0.00195, ~1 ulp) — its rounding is not RNE-compatible on gfx950. Do NOT
// substitute it in these paths.
// ---------------------------------------------------------------------------
__device__ __forceinline__ uint32_t f_to_bf(float f) {
    union { float f; uint32_t u; } v; v.f = f;
    uint32_t u = v.u;
    return (u + 0x7fffu + ((u >> 16) & 1u)) >> 16;
}
__device__ __forceinline__ float bf_to_f(uint32_t h) {
    union { uint32_t u; float f; } v; v.u = h << 16; return v.f;
}
__device__ __forceinline__ float2 bf2_to_f2(uint32_t u) {
    union { uint32_t u; float f; } a, b;
    a.u = u << 16; b.u = u & 0xffff0000u;
    float2 r; r.x = a.f; r.y = b.f; return r;
}
// acc[0..7] += (8 bf16 in u) * d   (still used by agg_final)
__device__ __forceinline__ void fma8(float* acc, uint4 u, float d) {
    float2 p0 = bf2_to_f2(u.x), p1 = bf2_to_f2(u.y);
    float2 p2 = bf2_to_f2(u.z), p3 = bf2_to_f2(u.w);
    acc[0] += p0.x * d; acc[1] += p0.y * d;
    acc[2] += p1.x * d; acc[3] += p1.y * d;
    acc[4] += p2.x * d; acc[5] += p2.y * d;
    acc[6] += p3.x * d; acc[7] += p3.y * d;
}

// ---------------------------------------------------------------------------
// int64-vs-int32 edge layout detection (reference uses int64).
// ---------------------------------------------------------------------------
__device__ __forceinline__ int detect64(const int* __restrict__ e32) {
    return (e32[1] | e32[3] | e32[5] | e32[7]) == 0;
}
__device__ __forceinline__ int edge_at(const void* edges, int is64, int idx) {
    if (is64) return (int)((const long long*)edges)[idx];
    return ((const int*)edges)[idx];
}

// ---------------------------------------------------------------------------
// W split body: convert W (f32) into MFMA B-frag hi/lo bf16 order.
// idx in [0, 40960): W1 (16384) | W2 (16384) | W3 (8192).
// ---------------------------------------------------------------------------
__device__ __forceinline__ void wsplit_body(
    int idx, const float* __restrict__ W1, const float* __restrict__ W2,
    const float* __restrict__ W3,
    uint16_t* w1h, uint16_t* w1l, uint16_t* w2h, uint16_t* w2l,
    uint16_t* w3h, uint16_t* w3l) {
    const float* W; uint16_t* oh; uint16_t* ol; int FOUT; int e;
    if (idx < 16384)      { W = W1; oh = w1h; ol = w1l; FOUT = 128; e = idx; }
    else if (idx < 32768) { W = W2; oh = w2h; ol = w2l; FOUT = 128; e = idx - 16384; }
    else                  { W = W3; oh = w3h; ol = w3l; FOUT = 64;  e = idx - 32768; }
    int j = e & 7;
    int lane = (e >> 3) & 63;
    int rem = e >> 9;
    int NT = FOUT >> 4;
    int nt = rem % NT, kc = rem / NT;
    int k = kc * 32 + ((lane >> 4) << 3) + j;
    int c = nt * 16 + (lane & 15);
    float v = W[(size_t)k * FOUT + c];
    uint32_t h = f_to_bf(v);
    uint32_t l = f_to_bf(v - bf_to_f(h));
    oh[e] = (uint16_t)h;
    ol[e] = (uint16_t)l;
}

// ---------------------------------------------------------------------------
// K1: blocks [0,sbcnt) scatter edges into dst buckets (bucket-LOCAL offsets;
// bucket_cur pre-zeroed by hipMemsetAsync, holds per-bucket totals after).
// R9: src loaded alongside dst in pass 1 and kept in registers.
// Blocks [sbcnt, sbcnt+160) do the W hi/lo split (needed by K2's gemm1).
// ---------------------------------------------------------------------------
__global__ __launch_bounds__(256) void scatter_wprep_kernel(
    const void* __restrict__ ei, int* __restrict__ bucket_cur,
    int2* __restrict__ buckets, int E, int sbcnt,
    const float* __restrict__ W1, const float* __restrict__ W2,
    const float* __restrict__ W3,
    uint16_t* w1h, uint16_t* w1l, uint16_t* w2h, uint16_t* w2l,
    uint16_t* w3h, uint16_t* w3l) {
    int tid = threadIdx.x;
    if ((int)blockIdx.x >= sbcnt) {
        int idx = (blockIdx.x - sbcnt) * 256 + tid;
        wsplit_body(idx, W1, W2, W3, w1h, w1l, w2h, w2l, w3h, w3l);
        return;
    }
    __shared__ int cnt[64];
    int base = blockIdx.x * CHUNK;
    int is64 = detect64((const int*)ei);
    if (tid < 64) cnt[tid] = 0;
    __syncthreads();
    int dloc[8], sloc[8];
#pragma unroll
    for (int it = 0; it < 8; it++) {
        int i = base + it * 256 + tid;
        int d = (i < E) ? edge_at(ei, is64, E + i) : -1;
        int s = (i < E) ? edge_at(ei, is64, i) : 0;
        dloc[it] = d;
        sloc[it] = s;
        if (d >= 0) atomicAdd(&cnt[d >> 10], 1);
    }
    __syncthreads();
    if (tid < 64) {
        int v = cnt[tid];
        cnt[tid] = atomicAdd(&bucket_cur[tid], v);   // bucket-local base
    }
    __syncthreads();
#pragma unroll
    for (int it = 0; it < 8; it++) {
        if (dloc[it] >= 0) {
            int b = dloc[it] >> 10;
            int p = atomicAdd(&cnt[b], 1);
            buckets[(size_t)b * CAP + p] = make_int2(sloc[it], dloc[it]);
        }
    }
}

// ---------------------------------------------------------------------------
// GEMM1 body: Y[i][:] = A[i][:] @ W (UNscaled), bf16 out. FOUT=128, K=128.
// R8: conversion staged through LDS (each wave converts only its kc-quarter).
// R9: next tile's A-quarter prefetched into registers (load rides under
// MFMA+store+sync). Identical RNE math and summation order.
// ---------------------------------------------------------------------------
__device__ __forceinline__ void gemm1_body(
    const float* __restrict__ A, const uint16_t* __restrict__ Wfhi,
    const uint16_t* __restrict__ Wflo, uint16_t* __restrict__ Yout,
    int n, int wid, int tile0, int tstride, int lane,
    uint16_t* __restrict__ hs, uint16_t* __restrict__ ls) {
    constexpr int NT = 8, NTW = 2, LDW = 136;
    int ntiles = (n + 15) >> 4;
    bf8_t wh[NTW][4], wl[NTW][4];
#pragma unroll
    for (int t = 0; t < NTW; t++) {
        int nt = wid * NTW + t;
#pragma unroll
        for (int kc = 0; kc < 4; kc++) {
            size_t b = ((size_t)(kc * NT + nt) * 64 + lane) * 8;
            wh[t][kc] = *(const bf8_t*)&Wfhi[b];
            wl[t][kc] = *(const bf8_t*)&Wflo[b];
        }
    }
    int row_in = lane & 15;
    int koff = (lane >> 4) << 3;
    int colb = lane & 15;
    int rq = (lane >> 4) << 2;
    int kcw = wid;   // this wave's conversion quarter
    float4 pv = {0, 0, 0, 0}, qv = {0, 0, 0, 0};
    if (tile0 < ntiles) {
        int arow = (tile0 << 4) + row_in; if (arow >= n) arow = n - 1;
        const float* ap = A + (size_t)arow * 128 + kcw * 32 + koff;
        pv = *(const float4*)ap;
        qv = *(const float4*)(ap + 4);
    }
    for (int tile = tile0; tile < ntiles; tile += tstride) {
        int R = tile << 4;
        {
            float vv[8] = {pv.x, pv.y, pv.z, pv.w, qv.x, qv.y, qv.z, qv.w};
            bf8_t H, L;
#pragma unroll
            for (int j = 0; j < 8; j++) {
                uint32_t h = f_to_bf(vv[j]);
                H[j] = (short)h;
                L[j] = (short)f_to_bf(vv[j] - bf_to_f(h));
            }
            *(bf8_t*)&hs[row_in * LDW + kcw * 32 + koff] = H;
            *(bf8_t*)&ls[row_in * LDW + kcw * 32 + koff] = L;
        }
        __syncthreads();
        int tnext = tile + tstride;
        if (tnext < ntiles) {
            int arow2 = (tnext << 4) + row_in; if (arow2 >= n) arow2 = n - 1;
            const float* ap2 = A + (size_t)arow2 * 128 + kcw * 32 + koff;
            pv = *(const float4*)ap2;
            qv = *(const float4*)(ap2 + 4);
        }
        bf8_t ah[4], al[4];
#pragma unroll
        for (int kc = 0; kc < 4; kc++) {
            ah[kc] = *(const bf8_t*)&hs[(lane & 15) * LDW + koff + kc * 32];
            al[kc] = *(const bf8_t*)&ls[(lane & 15) * LDW + koff + kc * 32];
        }
        f4_t acc[NTW];
#pragma unroll
        for (int t = 0; t < NTW; t++) acc[t] = (f4_t){0.f, 0.f, 0.f, 0.f};
#pragma unroll
        for (int kc = 0; kc < 4; kc++) {
#pragma unroll
            for (int t = 0; t < NTW; t++) {
                acc[t] = __builtin_amdgcn_mfma_f32_16x16x32_bf16(ah[kc], wh[t][kc], acc[t], 0, 0, 0);
                acc[t] = __builtin_amdgcn_mfma_f32_16x16x32_bf16(ah[kc], wl[t][kc], acc[t], 0, 0, 0);
                acc[t] = __builtin_amdgcn_mfma_f32_16x16x32_bf16(al[kc], wh[t][kc], acc[t], 0, 0, 0);
            }
        }
#pragma unroll
        for (int t = 0; t < NTW; t++) {
            int c = (wid * NTW + t) * 16 + colb;
#pragma unroll
            for (int r = 0; r < 4; r++) {
                int row = R + rq + r;
                if (row < n)
                    Yout[(size_t)row * 128 + c] = (uint16_t)f_to_bf(acc[t][r]);
            }
        }
        __syncthreads();
    }
}

// ---------------------------------------------------------------------------
// K2: blocks [0,nbuck) full per-bucket CSR build (MLP=4 batched, R6).
// Blocks [nbuck, ...) run gemm1. LDS overlaid (branch is block-uniform).
// ---------------------------------------------------------------------------
__global__ __launch_bounds__(256) void csrfill_gemm1_kernel(
    const int2* __restrict__ buckets, const int* __restrict__ bucket_cur,
    int* __restrict__ row_ptr, int* __restrict__ col,
    float* __restrict__ dinv, int nbuck,
    const float* __restrict__ x, const uint16_t* __restrict__ w1h,
    const uint16_t* __restrict__ w1l, uint16_t* __restrict__ y1, int n) {
    __shared__ __align__(16) char smem[12288];
    __shared__ int s_bo;
    int tid = threadIdx.x;
    if ((int)blockIdx.x >= nbuck) {
        uint16_t* hs = (uint16_t*)smem;            // 16*136*2 = 4352 B
        uint16_t* ls = (uint16_t*)(smem + 4352);   // 4352 B
        int lane = tid & 63, wid = tid >> 6;
        gemm1_body(x, w1h, w1l, y1, n, wid, blockIdx.x - nbuck,
                   gridDim.x - nbuck, lane, hs, ls);
        return;
    }
    int* cnt = (int*)smem;              // 4096 B
    int* sb  = (int*)(smem + 4096);     // 4096 B
    int* cur = (int*)(smem + 8192);     // 4096 B
    int b = blockIdx.x;
    int base = b << 10;
    int lim = min(1024, n - base);
    if (tid < 64) {
        int v = (tid < nbuck) ? bucket_cur[tid] : 0;
        int incl = v;
#pragma unroll
        for (int off = 1; off < 64; off <<= 1) {
            int t = __shfl_up(incl, off);
            if (tid >= off) incl += t;
        }
        int tot = __shfl(incl, nbuck - 1);
        int bo = (b > 0) ? __shfl(incl, b - 1) : 0;
        if (tid == 0) {
            s_bo = bo;
            if (b == nbuck - 1) row_ptr[n] = tot;
        }
    }
    int ecnt = bucket_cur[b];
    const int2* ebase = buckets + (size_t)b * CAP;
    for (int i = tid; i < 1024; i += 256) cnt[i] = 0;
    __syncthreads();
    {
        int i = tid;
        for (; i + 768 < ecnt; i += 1024) {
            int y0 = ebase[i].y;
            int y1_ = ebase[i + 256].y;
            int y2_ = ebase[i + 512].y;
            int y3_ = ebase[i + 768].y;
            atomicAdd(&cnt[y0 - base], 1);
            atomicAdd(&cnt[y1_ - base], 1);
            atomicAdd(&cnt[y2_ - base], 1);
            atomicAdd(&cnt[y3_ - base], 1);
        }
        for (; i < ecnt; i += 256)
            atomicAdd(&cnt[ebase[i].y - base], 1);
    }
    __syncthreads();
    for (int i = tid; i < lim; i += 256)
        dinv[base + i] = rsqrtf((float)(cnt[i] + 1));  // +1 = self-loop
    __syncthreads();
    int* a = cnt; int* s = sb;
    for (int st = 1; st < 1024; st <<= 1) {
        for (int i = tid; i < 1024; i += 256)
            s[i] = a[i] + ((i >= st) ? a[i - st] : 0);
        __syncthreads();
        int* t = a; a = s; s = t;
    }
    int bo = s_bo;
    for (int i = tid; i < lim; i += 256) {
        int v = ((i > 0) ? a[i - 1] : 0) + bo;
        row_ptr[base + i] = v;
        cur[i] = v;
    }
    __syncthreads();
    {
        int i = tid;
        for (; i + 768 < ecnt; i += 1024) {
            int2 e0 = ebase[i];
            int2 e1 = ebase[i + 256];
            int2 e2 = ebase[i + 512];
            int2 e3 = ebase[i + 768];
            int p0 = atomicAdd(&cur[e0.y - base], 1); col[p0] = e0.x;
            int p1 = atomicAdd(&cur[e1.y - base], 1); col[p1] = e1.x;
            int p2 = atomicAdd(&cur[e2.y - base], 1); col[p2] = e2.x;
            int p3 = atomicAdd(&cur[e3.y - base], 1); col[p3] = e3.x;
        }
        for (; i < ecnt; i += 256) {
            int2 e = ebase[i];
            int p = atomicAdd(&cur[e.y - base], 1);
            col[p] = e.x;
        }
    }
}

// ---------------------------------------------------------------------------
// R10: MFMA-BASED aggregate + next-layer GEMM. Block = 4 waves = 16 nodes.
// The block's edges are CONTIGUOUS in col[] (CSR rows base..base+16).
// Per 64-edge chunk: gather edge rows (bf16) into LDS [64][136], build
// selection matrix S[16 nodes][64 slots] (weight = dinv[src] as bf16 hi/lo
// for SRC_SCALE, exact 1.0 otherwise), then C[16][128] += S·Rows via
// 16x16x32 MFMA (waves split the 8 ch-tiles; 2 each, 2 K-chunks).
// Replaces ~17 VALU-cycles/edge (fma8+unpack+shuffles) with LDS+MFMA work
// (R2-R4: agg invariant to occupancy/MLP; VALU was co-binding at 47%).
// Self term = one extra diagonal chunk (slots 0-15, S=diag(w)).
// rows LDS zeroed once per block: stale garbage could be NaN; 0*NaN=NaN.
// B-frag = 8x ds_read_u16 (known ~8-way bank conflict, accepted this round).
// Epilogue: C frag -> relu(C*di+bias) -> hi/lo -> hs/ls LDS -> GEMM (as before).
// ---------------------------------------------------------------------------
template <int FOUT, bool SRC_SCALE>
__global__ __launch_bounds__(256) void agg_gemm_kernel(
    const uint16_t* __restrict__ Yin, const int* __restrict__ row_ptr,
    const int* __restrict__ col, const float* __restrict__ dinv,
    const float* __restrict__ bias,
    const uint16_t* __restrict__ Wfhi, const uint16_t* __restrict__ Wflo,
    uint16_t* __restrict__ Yout, int n) {
    constexpr int RLD = 136;   // rows pitch (u16): 272B, 16B-aligned
    constexpr int SLD = 72;    // S pitch (u16): 144B, 16B-aligned
    __shared__ uint16_t rows[64 * RLD];   // 17408 B
    __shared__ uint16_t Shi[16 * SLD];    // 2304 B
    __shared__ uint16_t Slo[16 * SLD];    // 2304 B
    __shared__ uint16_t hs[16 * 136];     // 4352 B
    __shared__ uint16_t ls[16 * 136];     // 4352 B
    __shared__ int   s_rp[17];
    __shared__ float s_di[16];
    __shared__ float s_bias[128];

    int tid = threadIdx.x, wid = tid >> 6, lane = tid & 63;
    int base = blockIdx.x * 16;
    int grp = lane & 15;
    const uint4* Y4 = (const uint4*)Yin;

    if (tid < 17) {
        int idx = base + tid; if (idx > n) idx = n;
        s_rp[tid] = row_ptr[idx];
    }
    if (tid >= 32 && tid < 48) {
        int m = tid - 32;
        s_di[m] = (base + m < n) ? dinv[base + m] : 0.f;
    }
    if (tid >= 64 && tid < 192) s_bias[tid - 64] = bias[tid - 64];
    // zero rows once (stale-garbage NaN hazard: 0 * NaN = NaN in MFMA)
    {
        uint4* r4 = (uint4*)rows;
        for (int i = tid; i < 64 * RLD / 8; i += 256) r4[i] = (uint4){0, 0, 0, 0};
    }
    __syncthreads();

    int e0 = s_rp[0], e1 = s_rp[16];
    f4_t acc[2] = {(f4_t){0.f, 0.f, 0.f, 0.f}, (f4_t){0.f, 0.f, 0.f, 0.f}};

    // ---- real edge chunks ----
    for (int cb = e0; cb < e1; cb += 64) {
        int cnt = min(64, e1 - cb);
        int sv = (cb + lane < e1) ? col[cb + lane] : 0;
        // zero S (both hi and lo)
        for (int i = tid; i < (16 * SLD) / 8; i += 256) {
            ((uint4*)Shi)[i] = (uint4){0, 0, 0, 0};
            ((uint4*)Slo)[i] = (uint4){0, 0, 0, 0};
        }
        __syncthreads();
        // wave0: build S (find owner node by binary search over s_rp)
        if (wid == 0 && lane < cnt) {
            int e = cb + lane;
            int lo = 0, hi = 16;
            while (hi - lo > 1) {
                int mid = (lo + hi) >> 1;
                if (s_rp[mid] <= e) lo = mid; else hi = mid;
            }
            float w = SRC_SCALE ? dinv[sv] : 1.f;
            uint32_t h = f_to_bf(w);
            Shi[lo * SLD + lane] = (uint16_t)h;
            if (SRC_SCALE)
                Slo[lo * SLD + lane] = (uint16_t)f_to_bf(w - bf_to_f(h));
        }
        // all waves: gather rows (wave w covers slots w*16 .. w*16+15)
#pragma unroll
        for (int i = 0; i < 4; i++) {
            int slot = wid * 16 + i * 4 + (lane >> 4);
            int src = __shfl(sv, slot);
            if (slot < cnt) {
                uint4 u = Y4[(size_t)src * 16 + grp];
                *(uint4*)&rows[slot * RLD + grp * 8] = u;
            }
        }
        __syncthreads();
        // MFMA: C[16][128] += S · Rows   (wave covers ch-tiles wid*2, wid*2+1)
#pragma unroll
        for (int t = 0; t < 2; t++) {
            int nt = wid * 2 + t;
#pragma unroll
            for (int kc = 0; kc < 2; kc++) {
                int kb = kc * 32 + ((lane >> 4) << 3);
                bf8_t bfrag;
#pragma unroll
                for (int j = 0; j < 8; j++)
                    bfrag[j] = (short)rows[(kb + j) * RLD + nt * 16 + grp];
                bf8_t ah = *(const bf8_t*)&Shi[grp * SLD + kb];
                acc[t] = __builtin_amdgcn_mfma_f32_16x16x32_bf16(ah, bfrag, acc[t], 0, 0, 0);
                if (SRC_SCALE) {
                    bf8_t al = *(const bf8_t*)&Slo[grp * SLD + kb];
                    acc[t] = __builtin_amdgcn_mfma_f32_16x16x32_bf16(al, bfrag, acc[t], 0, 0, 0);
                }
            }
        }
        __syncthreads();   // before next chunk overwrites S/rows
    }

    // ---- self chunk: slots 0..15 = own rows, S = diag(w) ----
    {
        for (int i = tid; i < (16 * SLD) / 8; i += 256) {
            ((uint4*)Shi)[i] = (uint4){0, 0, 0, 0};
            ((uint4*)Slo)[i] = (uint4){0, 0, 0, 0};
        }
        __syncthreads();
        if (wid == 0 && lane < 16) {
            float w = SRC_SCALE ? s_di[lane] : 1.f;
            uint32_t h = f_to_bf(w);
            Shi[lane * SLD + lane] = (uint16_t)h;
            if (SRC_SCALE)
                Slo[lane * SLD + lane] = (uint16_t)f_to_bf(w - bf_to_f(h));
        }
        {
            int slot = wid * 4 + (lane >> 4);
            int node = base + slot;
            if (node < n) {
                uint4 u = Y4[(size_t)node * 16 + grp];
                *(uint4*)&rows[slot * RLD + grp * 8] = u;
            } else {
                *(uint4*)&rows[slot * RLD + grp * 8] = (uint4){0, 0, 0, 0};
            }
        }
        __syncthreads();
#pragma unroll
        for (int t = 0; t < 2; t++) {
            int nt = wid * 2 + t;
            int kb = (lane >> 4) << 3;   // kc=0 only; S zero for k>=16
            bf8_t bfrag;
#pragma unroll
            for (int j = 0; j < 8; j++)
                bfrag[j] = (short)rows[(kb + j) * RLD + nt * 16 + grp];
            bf8_t ah = *(const bf8_t*)&Shi[grp * SLD + kb];
            acc[t] = __builtin_amdgcn_mfma_f32_16x16x32_bf16(ah, bfrag, acc[t], 0, 0, 0);
            if (SRC_SCALE) {
                bf8_t al = *(const bf8_t*)&Slo[grp * SLD + kb];
                acc[t] = __builtin_amdgcn_mfma_f32_16x16x32_bf16(al, bfrag, acc[t], 0, 0, 0);
            }
        }
    }

    // ---- epilogue: relu(C*di + bias), hi/lo split -> hs/ls ----
    // C frag layout (m89): ch-col = lane&15 (+nt*16), node-row = (lane>>4)*4 + r
    {
        int rq = (lane >> 4) << 2;
#pragma unroll
        for (int t = 0; t < 2; t++) {
            int nt = wid * 2 + t;
            int ch = nt * 16 + grp;
            float bb = s_bias[ch];
#pragma unroll
            for (int r = 0; r < 4; r++) {
                int m = rq + r;
                float v = fmaxf(acc[t][r] * s_di[m] + bb, 0.f);
                uint32_t h = f_to_bf(v);
                hs[m * 136 + ch] = (uint16_t)h;
                ls[m * 136 + ch] = (uint16_t)f_to_bf(v - bf_to_f(h));
            }
        }
    }
    __syncthreads();

    // ---- GEMM phase (unchanged structure) ----
    constexpr int NT = FOUT / 16;
    constexpr int NTW = NT / 4;   // 128 -> 2 col tiles/wave, 64 -> 1
    constexpr int LDW = 136;
    int cp = wid;
    bf8_t wwh[NTW][4], wwl[NTW][4];
#pragma unroll
    for (int t = 0; t < NTW; t++) {
        int nt = cp * NTW + t;
#pragma unroll
        for (int kc = 0; kc < 4; kc++) {
            size_t b = ((size_t)(kc * NT + nt) * 64 + lane) * 8;
            wwh[t][kc] = *(const bf8_t*)&Wfhi[b];
            wwl[t][kc] = *(const bf8_t*)&Wflo[b];
        }
    }
    int koff = (lane >> 4) << 3;
    int rq = (lane >> 4) << 2;
    bf8_t gah[4], gal[4];
#pragma unroll
    for (int kc = 0; kc < 4; kc++) {
        gah[kc] = *(const bf8_t*)&hs[grp * LDW + koff + kc * 32];
        gal[kc] = *(const bf8_t*)&ls[grp * LDW + koff + kc * 32];
    }
    f4_t gacc[NTW];
#pragma unroll
    for (int t = 0; t < NTW; t++) gacc[t] = (f4_t){0.f, 0.f, 0.f, 0.f};
#pragma unroll
    for (int kc = 0; kc < 4; kc++) {
#pragma unroll
        for (int t = 0; t < NTW; t++) {
            gacc[t] = __builtin_amdgcn_mfma_f32_16x16x32_bf16(gah[kc], wwh[t][kc], gacc[t], 0, 0, 0);
            gacc[t] = __builtin_amdgcn_mfma_f32_16x16x32_bf16(gah[kc], wwl[t][kc], gacc[t], 0, 0, 0);
            gacc[t] = __builtin_amdgcn_mfma_f32_16x16x32_bf16(gal[kc], wwh[t][kc], gacc[t], 0, 0, 0);
        }
    }
#pragma unroll
    for (int t = 0; t < NTW; t++) {
        int c = (cp * NTW + t) * 16 + grp;
#pragma unroll
        for (int r = 0; r < 4; r++) {
            int row = base + rq + r;
            if (row < n) {
                float v = gacc[t][r] * s_di[rq + r];
                Yout[(size_t)row * FOUT + c] = (uint16_t)f_to_bf(v);
            }
        }
    }
}

// ---------------------------------------------------------------------------
// Final aggregate (layer 3): 64 ch, fp32 out, no relu. One wave per node,
// 16B/lane gather: g=lane&7 (8 ch), j=lane>>3 (8 edge slots). Unchanged.
// ---------------------------------------------------------------------------
__global__ __launch_bounds__(256) void agg_final_kernel(
    const uint16_t* __restrict__ Y, const int* __restrict__ row_ptr,
    const int* __restrict__ col, const float* __restrict__ dinv,
    const float* __restrict__ bias, float* __restrict__ out, int n) {
    int w = blockIdx.x * 4 + (threadIdx.x >> 6);
    int lane = threadIdx.x & 63;
    if (w >= n) return;
    int g = lane & 7, j = lane >> 3;
    const uint4* Y4 = (const uint4*)Y;
    float4 bb0 = *(const float4*)&bias[g * 8];
    float4 bb1 = *(const float4*)&bias[g * 8 + 4];
    float bb[8] = {bb0.x, bb0.y, bb0.z, bb0.w, bb1.x, bb1.y, bb1.z, bb1.w};

    float aA[8] = {}, aB[8] = {};
    {
        uint4 su = Y4[(size_t)w * 8 + g];
        fma8(aA, su, (j == 0) ? 1.f : 0.f);
    }
    int start = row_ptr[w], end = row_ptr[w + 1];
    for (int b = start; b < end; b += 64) {
        int cnt = min(64, end - b);
        int sv = (b + lane < end) ? col[b + lane] : 0;
        for (int k = 0; k < cnt; k += 16) {
            int iA = k + j, iB = k + 8 + j;
            int sA = __shfl(sv, iA & 63);
            int sB = __shfl(sv, iB & 63);
            float dA = (iA < cnt) ? 1.f : 0.f;
            float dB = (iB < cnt) ? 1.f : 0.f;
            uint4 uA = Y4[(size_t)sA * 8 + g];
            uint4 uB = Y4[(size_t)sB * 8 + g];
            fma8(aA, uA, dA);
            fma8(aB, uB, dB);
        }
    }
    float o[8];
#pragma unroll
    for (int t = 0; t < 8; t++) o[t] = aA[t] + aB[t];
#pragma unroll
    for (int t = 0; t < 8; t++) o[t] += __shfl_xor(o[t], 8);
#pragma unroll
    for (int t = 0; t < 8; t++) o[t] += __shfl_xor(o[t], 16);
#pragma unroll
    for (int t = 0; t < 8; t++) o[t] += __shfl_xor(o[t], 32);
    float di = dinv[w];
#pragma unroll
    for (int t = 0; t < 8; t++) o[t] = o[t] * di + bb[t];
    if (j == 0) {
        float4 o0 = {o[0], o[1], o[2], o[3]};
        float4 o1 = {o[4], o[5], o[6], o[7]};
        *(float4*)&out[(size_t)w * 64 + g * 8] = o0;
        *(float4*)&out[(size_t)w * 64 + g * 8 + 4] = o1;
    }
}

extern "C" void kernel_launch(void* const* d_in, const int* in_sizes, int n_in,
                              void* d_out, int out_size, void* d_ws, size_t ws_size,
                              hipStream_t stream) {
    const float* x  = (const float*)d_in[0];
    const void*  ei = d_in[1];
    const float* W1 = (const float*)d_in[2];
    const float* b1 = (const float*)d_in[3];
    const float* W2 = (const float*)d_in[4];
    const float* b2 = (const float*)d_in[5];
    const float* W3 = (const float*)d_in[6];
    const float* b3 = (const float*)d_in[7];
    int n = in_sizes[0] / 128;     // 50000
    int E = in_sizes[1] / 2;       // 800000
    int nbuck = (n + 1023) >> 10;  // 49 (<= 64)

    char* p = (char*)d_ws;
    auto carve = [&](size_t bytes) {
        char* r = p;
        p += (bytes + 255) & ~(size_t)255;
        return r;
    };
    float*    dinv       = (float*)carve((size_t)n * 4);
    int*      row_ptr    = (int*)carve((size_t)(n + 1) * 4);
    int*      bucket_cur = (int*)carve(64 * 4);
    int*      col        = (int*)carve((size_t)E * 4);
    int2*     buckets    = (int2*)carve((size_t)64 * CAP * 8);
    uint16_t* y1         = (uint16_t*)carve((size_t)n * 128 * 2);
    uint16_t* y2         = (uint16_t*)carve((size_t)n * 128 * 2);
    uint16_t* y3         = (uint16_t*)carve((size_t)n * 64 * 2);
    uint16_t* w1h        = (uint16_t*)carve(128 * 128 * 2);
    uint16_t* w1l        = (uint16_t*)carve(128 * 128 * 2);
    uint16_t* w2h        = (uint16_t*)carve(128 * 128 * 2);
    uint16_t* w2l        = (uint16_t*)carve(128 * 128 * 2);
    uint16_t* w3h        = (uint16_t*)carve(128 * 64 * 2);
    uint16_t* w3l        = (uint16_t*)carve(128 * 64 * 2);

    int sbcnt = (E + CHUNK - 1) / CHUNK;   // 391 scatter blocks
    int fb = (n + 15) / 16;                // 3125 fused blocks

    // bucket cursors start at 0 (bucket-local offsets)
    hipMemsetAsync(bucket_cur, 0, 64 * 4, stream);
    // K1: edge scatter || W hi/lo split
    scatter_wprep_kernel<<<sbcnt + 160, 256, 0, stream>>>(
        ei, bucket_cur, buckets, E, sbcnt,
        W1, W2, W3, w1h, w1l, w2h, w2l, w3h, w3l);
    // K2: per-bucket CSR build (hist+scan+fill, MLP=4 batched) || gemm1
    csrfill_gemm1_kernel<<<nbuck + 782, 256, 0, stream>>>(
        buckets, bucket_cur, row_ptr, col, dinv, nbuck,
        x, w1h, w1l, y1, n);
    // K4: agg1 (src-scaled, MFMA agg) + gemm2 -> y2 (scaled)
    agg_gemm_kernel<128, true><<<fb, 256, 0, stream>>>(
        y1, row_ptr, col, dinv, b1, w2h, w2l, y2, n);
    // K5: agg2 (MFMA agg) + gemm3 -> y3 (scaled)
    agg_gemm_kernel<64, false><<<fb, 256, 0, stream>>>(
        y2, row_ptr, col, dinv, b2, w3h, w3l, y3, n);
    // K6: final aggregate -> d_out
    agg_final_kernel<<<(n + 3) / 4, 256, 0, stream>>>(
        y3, row_ptr, col, dinv, b3, (float*)d_out, n);
}

// Round 12
// 231.318 us; speedup vs baseline: 1.0789x; 1.0789x over previous
//
#include <hip/hip_runtime.h>
#include <cstdint>

#define CAP 32768    // slots per bucket (expected fill ~16.3k)
#define CHUNK 2048   // edges per scatter block

typedef __attribute__((ext_vector_type(8))) short bf8_t;   // 8 bf16 = 4 VGPRs
typedef __attribute__((ext_vector_type(4))) float f4_t;

// ---------------------------------------------------------------------------
// bf16 helpers (manual integer RNE).
// R7 lesson: v_cvt_pk_bf16_f32 inline-asm FAILED refcheck (absmax 0.0244 vs
// 0.00195, ~1 ulp) — its rounding is not RNE-compatible on gfx950. Do NOT
// substitute it in these paths.
// R10/11 lesson: MFMA-based aggregation (S-matrix) REGRESSED 48->59.7us:
// VALUBusy collapsed 47->19% yet time rose — agg is pinned by the random-
// gather memory path (~2TB/s effective on scattered 256B rows), NOT VALU.
// Five structural variants (MLP, occupancy, pk-math, wave-per-node, MFMA)
// all land >= 48us. Do not re-litigate the agg loop.
// ---------------------------------------------------------------------------
__device__ __forceinline__ uint32_t f_to_bf(float f) {
    union { float f; uint32_t u; } v; v.f = f;
    uint32_t u = v.u;
    return (u + 0x7fffu + ((u >> 16) & 1u)) >> 16;
}
__device__ __forceinline__ float bf_to_f(uint32_t h) {
    union { uint32_t u; float f; } v; v.u = h << 16; return v.f;
}
__device__ __forceinline__ float2 bf2_to_f2(uint32_t u) {
    union { uint32_t u; float f; } a, b;
    a.u = u << 16; b.u = u & 0xffff0000u;
    float2 r; r.x = a.f; r.y = b.f; return r;
}
// acc[0..7] += (8 bf16 in u) * d
__device__ __forceinline__ void fma8(float* acc, uint4 u, float d) {
    float2 p0 = bf2_to_f2(u.x), p1 = bf2_to_f2(u.y);
    float2 p2 = bf2_to_f2(u.z), p3 = bf2_to_f2(u.w);
    acc[0] += p0.x * d; acc[1] += p0.y * d;
    acc[2] += p1.x * d; acc[3] += p1.y * d;
    acc[4] += p2.x * d; acc[5] += p2.y * d;
    acc[6] += p3.x * d; acc[7] += p3.y * d;
}

// ---------------------------------------------------------------------------
// int64-vs-int32 edge layout detection (reference uses int64).
// ---------------------------------------------------------------------------
__device__ __forceinline__ int detect64(const int* __restrict__ e32) {
    return (e32[1] | e32[3] | e32[5] | e32[7]) == 0;
}
__device__ __forceinline__ int edge_at(const void* edges, int is64, int idx) {
    if (is64) return (int)((const long long*)edges)[idx];
    return ((const int*)edges)[idx];
}

// ---------------------------------------------------------------------------
// W split body: convert W (f32) into MFMA B-frag hi/lo bf16 order.
// idx in [0, 40960): W1 (16384) | W2 (16384) | W3 (8192).
// ---------------------------------------------------------------------------
__device__ __forceinline__ void wsplit_body(
    int idx, const float* __restrict__ W1, const float* __restrict__ W2,
    const float* __restrict__ W3,
    uint16_t* w1h, uint16_t* w1l, uint16_t* w2h, uint16_t* w2l,
    uint16_t* w3h, uint16_t* w3l) {
    const float* W; uint16_t* oh; uint16_t* ol; int FOUT; int e;
    if (idx < 16384)      { W = W1; oh = w1h; ol = w1l; FOUT = 128; e = idx; }
    else if (idx < 32768) { W = W2; oh = w2h; ol = w2l; FOUT = 128; e = idx - 16384; }
    else                  { W = W3; oh = w3h; ol = w3l; FOUT = 64;  e = idx - 32768; }
    int j = e & 7;
    int lane = (e >> 3) & 63;
    int rem = e >> 9;
    int NT = FOUT >> 4;
    int nt = rem % NT, kc = rem / NT;
    int k = kc * 32 + ((lane >> 4) << 3) + j;
    int c = nt * 16 + (lane & 15);
    float v = W[(size_t)k * FOUT + c];
    uint32_t h = f_to_bf(v);
    uint32_t l = f_to_bf(v - bf_to_f(h));
    oh[e] = (uint16_t)h;
    ol[e] = (uint16_t)l;
}

// ---------------------------------------------------------------------------
// K1: blocks [0,sbcnt) scatter edges into dst buckets (bucket-LOCAL offsets;
// bucket_cur pre-zeroed by hipMemsetAsync, holds per-bucket totals after).
// R9: src loaded alongside dst in pass 1 and kept in registers — removes
// the second 6.4 MB edge-array read pass + its latency chain.
// Blocks [sbcnt, sbcnt+160) do the W hi/lo split (needed by K2's gemm1).
// ---------------------------------------------------------------------------
__global__ __launch_bounds__(256) void scatter_wprep_kernel(
    const void* __restrict__ ei, int* __restrict__ bucket_cur,
    int2* __restrict__ buckets, int E, int sbcnt,
    const float* __restrict__ W1, const float* __restrict__ W2,
    const float* __restrict__ W3,
    uint16_t* w1h, uint16_t* w1l, uint16_t* w2h, uint16_t* w2l,
    uint16_t* w3h, uint16_t* w3l) {
    int tid = threadIdx.x;
    if ((int)blockIdx.x >= sbcnt) {
        int idx = (blockIdx.x - sbcnt) * 256 + tid;
        wsplit_body(idx, W1, W2, W3, w1h, w1l, w2h, w2l, w3h, w3l);
        return;
    }
    __shared__ int cnt[64];
    int base = blockIdx.x * CHUNK;
    int is64 = detect64((const int*)ei);
    if (tid < 64) cnt[tid] = 0;
    __syncthreads();
    int dloc[8], sloc[8];
#pragma unroll
    for (int it = 0; it < 8; it++) {
        int i = base + it * 256 + tid;
        int d = (i < E) ? edge_at(ei, is64, E + i) : -1;
        int s = (i < E) ? edge_at(ei, is64, i) : 0;
        dloc[it] = d;
        sloc[it] = s;
        if (d >= 0) atomicAdd(&cnt[d >> 10], 1);
    }
    __syncthreads();
    if (tid < 64) {
        int v = cnt[tid];
        cnt[tid] = atomicAdd(&bucket_cur[tid], v);   // bucket-local base
    }
    __syncthreads();
#pragma unroll
    for (int it = 0; it < 8; it++) {
        if (dloc[it] >= 0) {
            int b = dloc[it] >> 10;
            int p = atomicAdd(&cnt[b], 1);
            buckets[(size_t)b * CAP + p] = make_int2(sloc[it], dloc[it]);
        }
    }
}

// ---------------------------------------------------------------------------
// GEMM1 body: Y[i][:] = A[i][:] @ W (UNscaled), bf16 out. FOUT=128, K=128.
// R8: conversion staged through LDS (each wave converts only its kc-quarter,
// 4x less duplicate VALU). R9: tile loop software-pipelined — tile t+1's
// A-quarter is prefetched into registers right after the first sync of
// tile t, hiding the ~500cy global load under MFMA+store+sync. Identical
// RNE math and summation order.
// ---------------------------------------------------------------------------
__device__ __forceinline__ void gemm1_body(
    const float* __restrict__ A, const uint16_t* __restrict__ Wfhi,
    const uint16_t* __restrict__ Wflo, uint16_t* __restrict__ Yout,
    int n, int wid, int tile0, int tstride, int lane,
    uint16_t* __restrict__ hs, uint16_t* __restrict__ ls) {
    constexpr int NT = 8, NTW = 2, LDW = 136;
    int ntiles = (n + 15) >> 4;
    bf8_t wh[NTW][4], wl[NTW][4];
#pragma unroll
    for (int t = 0; t < NTW; t++) {
        int nt = wid * NTW + t;
#pragma unroll
        for (int kc = 0; kc < 4; kc++) {
            size_t b = ((size_t)(kc * NT + nt) * 64 + lane) * 8;
            wh[t][kc] = *(const bf8_t*)&Wfhi[b];
            wl[t][kc] = *(const bf8_t*)&Wflo[b];
        }
    }
    int row_in = lane & 15;
    int koff = (lane >> 4) << 3;
    int colb = lane & 15;
    int rq = (lane >> 4) << 2;
    int kcw = wid;   // this wave's conversion quarter
    float4 pv = {0, 0, 0, 0}, qv = {0, 0, 0, 0};
    if (tile0 < ntiles) {
        int arow = (tile0 << 4) + row_in; if (arow >= n) arow = n - 1;
        const float* ap = A + (size_t)arow * 128 + kcw * 32 + koff;
        pv = *(const float4*)ap;
        qv = *(const float4*)(ap + 4);
    }
    for (int tile = tile0; tile < ntiles; tile += tstride) {
        int R = tile << 4;
        {
            float vv[8] = {pv.x, pv.y, pv.z, pv.w, qv.x, qv.y, qv.z, qv.w};
            bf8_t H, L;
#pragma unroll
            for (int j = 0; j < 8; j++) {
                uint32_t h = f_to_bf(vv[j]);
                H[j] = (short)h;
                L[j] = (short)f_to_bf(vv[j] - bf_to_f(h));
            }
            *(bf8_t*)&hs[row_in * LDW + kcw * 32 + koff] = H;
            *(bf8_t*)&ls[row_in * LDW + kcw * 32 + koff] = L;
        }
        __syncthreads();
        int tnext = tile + tstride;
        if (tnext < ntiles) {
            int arow2 = (tnext << 4) + row_in; if (arow2 >= n) arow2 = n - 1;
            const float* ap2 = A + (size_t)arow2 * 128 + kcw * 32 + koff;
            pv = *(const float4*)ap2;
            qv = *(const float4*)(ap2 + 4);
        }
        bf8_t ah[4], al[4];
#pragma unroll
        for (int kc = 0; kc < 4; kc++) {
            ah[kc] = *(const bf8_t*)&hs[(lane & 15) * LDW + koff + kc * 32];
            al[kc] = *(const bf8_t*)&ls[(lane & 15) * LDW + koff + kc * 32];
        }
        f4_t acc[NTW];
#pragma unroll
        for (int t = 0; t < NTW; t++) acc[t] = (f4_t){0.f, 0.f, 0.f, 0.f};
#pragma unroll
        for (int kc = 0; kc < 4; kc++) {
#pragma unroll
            for (int t = 0; t < NTW; t++) {
                acc[t] = __builtin_amdgcn_mfma_f32_16x16x32_bf16(ah[kc], wh[t][kc], acc[t], 0, 0, 0);
                acc[t] = __builtin_amdgcn_mfma_f32_16x16x32_bf16(ah[kc], wl[t][kc], acc[t], 0, 0, 0);
                acc[t] = __builtin_amdgcn_mfma_f32_16x16x32_bf16(al[kc], wh[t][kc], acc[t], 0, 0, 0);
            }
        }
#pragma unroll
        for (int t = 0; t < NTW; t++) {
            int c = (wid * NTW + t) * 16 + colb;
#pragma unroll
            for (int r = 0; r < 4; r++) {
                int row = R + rq + r;
                if (row < n)
                    Yout[(size_t)row * 128 + c] = (uint16_t)f_to_bf(acc[t][r]);
            }
        }
        __syncthreads();
    }
}

// ---------------------------------------------------------------------------
// K2: blocks [0,nbuck) do the FULL per-bucket CSR build (histogram + dinv +
// scan + global offset from bucket_cur totals + col fill), MLP=4 batched
// loads (R6: the serial MLP=1 version was a 50µs tail at 10% occupancy).
// Blocks [nbuck, ...) run gemm1 (y1 = x@W1, unscaled).
// LDS overlaid between the two branches (branch is block-uniform):
// CSR needs 12 KB (cnt/sb/cur), gemm1 needs 8.7 KB (hs/ls).
// ---------------------------------------------------------------------------
__global__ __launch_bounds__(256) void csrfill_gemm1_kernel(
    const int2* __restrict__ buckets, const int* __restrict__ bucket_cur,
    int* __restrict__ row_ptr, int* __restrict__ col,
    float* __restrict__ dinv, int nbuck,
    const float* __restrict__ x, const uint16_t* __restrict__ w1h,
    const uint16_t* __restrict__ w1l, uint16_t* __restrict__ y1, int n) {
    __shared__ __align__(16) char smem[12288];
    __shared__ int s_bo;
    int tid = threadIdx.x;
    if ((int)blockIdx.x >= nbuck) {
        uint16_t* hs = (uint16_t*)smem;            // 16*136*2 = 4352 B
        uint16_t* ls = (uint16_t*)(smem + 4352);   // 4352 B
        int lane = tid & 63, wid = tid >> 6;
        gemm1_body(x, w1h, w1l, y1, n, wid, blockIdx.x - nbuck,
                   gridDim.x - nbuck, lane, hs, ls);
        return;
    }
    int* cnt = (int*)smem;              // 4096 B
    int* sb  = (int*)(smem + 4096);     // 4096 B
    int* cur = (int*)(smem + 8192);     // 4096 B
    int b = blockIdx.x;
    int base = b << 10;
    int lim = min(1024, n - base);
    // wave0: global bucket-offset prefix from bucket_cur totals
    if (tid < 64) {
        int v = (tid < nbuck) ? bucket_cur[tid] : 0;
        int incl = v;
#pragma unroll
        for (int off = 1; off < 64; off <<= 1) {
            int t = __shfl_up(incl, off);
            if (tid >= off) incl += t;
        }
        int tot = __shfl(incl, nbuck - 1);
        int bo = (b > 0) ? __shfl(incl, b - 1) : 0;
        if (tid == 0) {
            s_bo = bo;
            if (b == nbuck - 1) row_ptr[n] = tot;
        }
    }
    int ecnt = bucket_cur[b];
    const int2* ebase = buckets + (size_t)b * CAP;
    for (int i = tid; i < 1024; i += 256) cnt[i] = 0;
    __syncthreads();
    // histogram, 4x batched loads (MLP=4)
    {
        int i = tid;
        for (; i + 768 < ecnt; i += 1024) {
            int y0 = ebase[i].y;
            int y1_ = ebase[i + 256].y;
            int y2_ = ebase[i + 512].y;
            int y3_ = ebase[i + 768].y;
            atomicAdd(&cnt[y0 - base], 1);
            atomicAdd(&cnt[y1_ - base], 1);
            atomicAdd(&cnt[y2_ - base], 1);
            atomicAdd(&cnt[y3_ - base], 1);
        }
        for (; i < ecnt; i += 256)
            atomicAdd(&cnt[ebase[i].y - base], 1);
    }
    __syncthreads();
    for (int i = tid; i < lim; i += 256)
        dinv[base + i] = rsqrtf((float)(cnt[i] + 1));  // +1 = self-loop
    __syncthreads();
    int* a = cnt; int* s = sb;
    for (int st = 1; st < 1024; st <<= 1) {
        for (int i = tid; i < 1024; i += 256)
            s[i] = a[i] + ((i >= st) ? a[i - st] : 0);
        __syncthreads();
        int* t = a; a = s; s = t;
    }
    int bo = s_bo;
    for (int i = tid; i < lim; i += 256) {
        int v = ((i > 0) ? a[i - 1] : 0) + bo;
        row_ptr[base + i] = v;
        cur[i] = v;
    }
    __syncthreads();
    // col fill, 4x batched loads (MLP=4)
    {
        int i = tid;
        for (; i + 768 < ecnt; i += 1024) {
            int2 e0 = ebase[i];
            int2 e1 = ebase[i + 256];
            int2 e2 = ebase[i + 512];
            int2 e3 = ebase[i + 768];
            int p0 = atomicAdd(&cur[e0.y - base], 1); col[p0] = e0.x;
            int p1 = atomicAdd(&cur[e1.y - base], 1); col[p1] = e1.x;
            int p2 = atomicAdd(&cur[e2.y - base], 1); col[p2] = e2.x;
            int p3 = atomicAdd(&cur[e3.y - base], 1); col[p3] = e3.x;
        }
        for (; i < ecnt; i += 256) {
            int2 e = ebase[i];
            int p = atomicAdd(&cur[e.y - base], 1);
            col[p] = e.x;
        }
    }
}

// ---------------------------------------------------------------------------
// Fused aggregate + next-layer GEMM. Block = 4 waves = 16 nodes.
// EXACT R1 configuration (best harness-verified: 48.0 µs): width-8 slots,
// scalar fma8, direct dinv broadcast loads, q-loop over 4 nodes/wave.
// R2-R4 + R10/11 established the agg loop is pinned by the random-gather
// memory path (~2 TB/s effective), invariant to occupancy (45->58%),
// per-wave MLP (2->4), VALU style (scalar/pk), and MFMA-offload (VALUBusy
// 47->19% yet 48->59.7us). This is the floor for this access pattern.
// Agg phase (CH=128 input, 16B/lane gather): lane = (j=lane>>4 edge slot,
// g=lane&15 channel group of 8). One dwordx4 load fetches 4 edge rows/wave.
// Butterfly (xor 16,32) reduces j; lanes j==0 write h hi/lo to LDS.
// GEMM phase: 16-row MFMA tile; Yout = (h @ W) * dinv, bf16.
// SRC_SCALE: gathered rows scaled by dinv[src] (layer 1, y1 unscaled).
// ---------------------------------------------------------------------------
template <int FOUT, bool SRC_SCALE>
__global__ __launch_bounds__(256) void agg_gemm_kernel(
    const uint16_t* __restrict__ Yin, const int* __restrict__ row_ptr,
    const int* __restrict__ col, const float* __restrict__ dinv,
    const float* __restrict__ bias,
    const uint16_t* __restrict__ Wfhi, const uint16_t* __restrict__ Wflo,
    uint16_t* __restrict__ Yout, int n) {
    __shared__ uint4 hs4[16 * 17];   // 16 rows x 136 uint16 (pad 8)
    __shared__ uint4 ls4[16 * 17];
    int tid = threadIdx.x, wid = tid >> 6, lane = tid & 63;
    int base = blockIdx.x * 16;
    int g = lane & 15, j = lane >> 4;
    const uint4* Y4 = (const uint4*)Yin;

    // bias channels for my group (invariant over q)
    float4 bb0 = *(const float4*)&bias[g * 8];
    float4 bb1 = *(const float4*)&bias[g * 8 + 4];
    float bb[8] = {bb0.x, bb0.y, bb0.z, bb0.w, bb1.x, bb1.y, bb1.z, bb1.w};

    for (int q = 0; q < 4; q++) {
        int r = wid * 4 + q, node = base + r;
        uint4 ph = (uint4){0, 0, 0, 0}, pl = (uint4){0, 0, 0, 0};
        if (node < n) {
            float di = dinv[node];
            float aA[8] = {}, aB[8] = {};
            // self term: only j==0 lanes contribute
            {
                float sd = (j == 0) ? (SRC_SCALE ? di : 1.f) : 0.f;
                uint4 su = Y4[(size_t)node * 16 + g];
                fma8(aA, su, sd);
            }
            int start = row_ptr[node], end = row_ptr[node + 1];
            for (int b = start; b < end; b += 64) {
                int cnt = min(64, end - b);
                int sv = (b + lane < end) ? col[b + lane] : 0;
                for (int k = 0; k < cnt; k += 8) {
                    int iA = k + j, iB = k + 4 + j;
                    int sA = __shfl(sv, iA & 63);
                    int sB = __shfl(sv, iB & 63);
                    float dA = (iA < cnt) ? (SRC_SCALE ? dinv[sA] : 1.f) : 0.f;
                    float dB = (iB < cnt) ? (SRC_SCALE ? dinv[sB] : 1.f) : 0.f;
                    uint4 uA = Y4[(size_t)sA * 16 + g];
                    uint4 uB = Y4[(size_t)sB * 16 + g];
                    fma8(aA, uA, dA);
                    fma8(aB, uB, dB);
                }
            }
            float o[8];
#pragma unroll
            for (int t = 0; t < 8; t++) o[t] = aA[t] + aB[t];
#pragma unroll
            for (int t = 0; t < 8; t++) o[t] += __shfl_xor(o[t], 16);
#pragma unroll
            for (int t = 0; t < 8; t++) o[t] += __shfl_xor(o[t], 32);
            uint32_t hh[8];
#pragma unroll
            for (int t = 0; t < 8; t++) {
                o[t] = fmaxf(o[t] * di + bb[t], 0.f);   // relu (layers 1,2)
                hh[t] = f_to_bf(o[t]);
            }
            ph = (uint4){hh[0] | (hh[1] << 16), hh[2] | (hh[3] << 16),
                         hh[4] | (hh[5] << 16), hh[6] | (hh[7] << 16)};
            uint32_t ll[8];
#pragma unroll
            for (int t = 0; t < 8; t++) ll[t] = f_to_bf(o[t] - bf_to_f(hh[t]));
            pl = (uint4){ll[0] | (ll[1] << 16), ll[2] | (ll[3] << 16),
                         ll[4] | (ll[5] << 16), ll[6] | (ll[7] << 16)};
        }
        if (j == 0) {
            hs4[r * 17 + g] = ph;
            ls4[r * 17 + g] = pl;
        }
    }
    __syncthreads();

    // ---- GEMM phase ----
    const uint16_t* hs = (const uint16_t*)hs4;
    const uint16_t* ls = (const uint16_t*)ls4;
    constexpr int NT = FOUT / 16;
    constexpr int NTW = NT / 4;   // 128 -> 2 col tiles/wave, 64 -> 1
    constexpr int LDW = 136;
    int cp = wid;
    bf8_t wh[NTW][4], wl[NTW][4];
#pragma unroll
    for (int t = 0; t < NTW; t++) {
        int nt = cp * NTW + t;
#pragma unroll
        for (int kc = 0; kc < 4; kc++) {
            size_t b = ((size_t)(kc * NT + nt) * 64 + lane) * 8;
            wh[t][kc] = *(const bf8_t*)&Wfhi[b];
            wl[t][kc] = *(const bf8_t*)&Wflo[b];
        }
    }
    int koff = (lane >> 4) << 3;
    int colb = lane & 15;
    int rq = (lane >> 4) << 2;
    bf8_t ah[4], al[4];
#pragma unroll
    for (int kc = 0; kc < 4; kc++) {
        ah[kc] = *(const bf8_t*)(hs + (lane & 15) * LDW + koff + kc * 32);
        al[kc] = *(const bf8_t*)(ls + (lane & 15) * LDW + koff + kc * 32);
    }
    f4_t acc[NTW];
#pragma unroll
    for (int t = 0; t < NTW; t++) acc[t] = (f4_t){0.f, 0.f, 0.f, 0.f};
#pragma unroll
    for (int kc = 0; kc < 4; kc++) {
#pragma unroll
        for (int t = 0; t < NTW; t++) {
            acc[t] = __builtin_amdgcn_mfma_f32_16x16x32_bf16(ah[kc], wh[t][kc], acc[t], 0, 0, 0);
            acc[t] = __builtin_amdgcn_mfma_f32_16x16x32_bf16(ah[kc], wl[t][kc], acc[t], 0, 0, 0);
            acc[t] = __builtin_amdgcn_mfma_f32_16x16x32_bf16(al[kc], wh[t][kc], acc[t], 0, 0, 0);
        }
    }
#pragma unroll
    for (int t = 0; t < NTW; t++) {
        int c = (cp * NTW + t) * 16 + colb;
#pragma unroll
        for (int r = 0; r < 4; r++) {
            int row = base + rq + r;
            if (row < n) {
                float v = acc[t][r] * dinv[row];
                Yout[(size_t)row * FOUT + c] = (uint16_t)f_to_bf(v);
            }
        }
    }
}

// ---------------------------------------------------------------------------
// Final aggregate (layer 3): 64 ch, fp32 out, no relu. One wave per node,
// 16B/lane gather: g=lane&7 (8 ch), j=lane>>3 (8 edge slots).
// ---------------------------------------------------------------------------
__global__ __launch_bounds__(256) void agg_final_kernel(
    const uint16_t* __restrict__ Y, const int* __restrict__ row_ptr,
    const int* __restrict__ col, const float* __restrict__ dinv,
    const float* __restrict__ bias, float* __restrict__ out, int n) {
    int w = blockIdx.x * 4 + (threadIdx.x >> 6);
    int lane = threadIdx.x & 63;
    if (w >= n) return;
    int g = lane & 7, j = lane >> 3;
    const uint4* Y4 = (const uint4*)Y;
    float4 bb0 = *(const float4*)&bias[g * 8];
    float4 bb1 = *(const float4*)&bias[g * 8 + 4];
    float bb[8] = {bb0.x, bb0.y, bb0.z, bb0.w, bb1.x, bb1.y, bb1.z, bb1.w};

    float aA[8] = {}, aB[8] = {};
    {
        uint4 su = Y4[(size_t)w * 8 + g];
        fma8(aA, su, (j == 0) ? 1.f : 0.f);
    }
    int start = row_ptr[w], end = row_ptr[w + 1];
    for (int b = start; b < end; b += 64) {
        int cnt = min(64, end - b);
        int sv = (b + lane < end) ? col[b + lane] : 0;
        for (int k = 0; k < cnt; k += 16) {
            int iA = k + j, iB = k + 8 + j;
            int sA = __shfl(sv, iA & 63);
            int sB = __shfl(sv, iB & 63);
            float dA = (iA < cnt) ? 1.f : 0.f;
            float dB = (iB < cnt) ? 1.f : 0.f;
            uint4 uA = Y4[(size_t)sA * 8 + g];
            uint4 uB = Y4[(size_t)sB * 8 + g];
            fma8(aA, uA, dA);
            fma8(aB, uB, dB);
        }
    }
    float o[8];
#pragma unroll
    for (int t = 0; t < 8; t++) o[t] = aA[t] + aB[t];
#pragma unroll
    for (int t = 0; t < 8; t++) o[t] += __shfl_xor(o[t], 8);
#pragma unroll
    for (int t = 0; t < 8; t++) o[t] += __shfl_xor(o[t], 16);
#pragma unroll
    for (int t = 0; t < 8; t++) o[t] += __shfl_xor(o[t], 32);
    float di = dinv[w];
#pragma unroll
    for (int t = 0; t < 8; t++) o[t] = o[t] * di + bb[t];
    if (j == 0) {
        float4 o0 = {o[0], o[1], o[2], o[3]};
        float4 o1 = {o[4], o[5], o[6], o[7]};
        *(float4*)&out[(size_t)w * 64 + g * 8] = o0;
        *(float4*)&out[(size_t)w * 64 + g * 8 + 4] = o1;
    }
}

extern "C" void kernel_launch(void* const* d_in, const int* in_sizes, int n_in,
                              void* d_out, int out_size, void* d_ws, size_t ws_size,
                              hipStream_t stream) {
    const float* x  = (const float*)d_in[0];
    const void*  ei = d_in[1];
    const float* W1 = (const float*)d_in[2];
    const float* b1 = (const float*)d_in[3];
    const float* W2 = (const float*)d_in[4];
    const float* b2 = (const float*)d_in[5];
    const float* W3 = (const float*)d_in[6];
    const float* b3 = (const float*)d_in[7];
    int n = in_sizes[0] / 128;     // 50000
    int E = in_sizes[1] / 2;       // 800000
    int nbuck = (n + 1023) >> 10;  // 49 (<= 64)

    char* p = (char*)d_ws;
    auto carve = [&](size_t bytes) {
        char* r = p;
        p += (bytes + 255) & ~(size_t)255;
        return r;
    };
    float*    dinv       = (float*)carve((size_t)n * 4);
    int*      row_ptr    = (int*)carve((size_t)(n + 1) * 4);
    int*      bucket_cur = (int*)carve(64 * 4);
    int*      col        = (int*)carve((size_t)E * 4);
    int2*     buckets    = (int2*)carve((size_t)64 * CAP * 8);
    uint16_t* y1         = (uint16_t*)carve((size_t)n * 128 * 2);
    uint16_t* y2         = (uint16_t*)carve((size_t)n * 128 * 2);
    uint16_t* y3         = (uint16_t*)carve((size_t)n * 64 * 2);
    uint16_t* w1h        = (uint16_t*)carve(128 * 128 * 2);
    uint16_t* w1l        = (uint16_t*)carve(128 * 128 * 2);
    uint16_t* w2h        = (uint16_t*)carve(128 * 128 * 2);
    uint16_t* w2l        = (uint16_t*)carve(128 * 128 * 2);
    uint16_t* w3h        = (uint16_t*)carve(128 * 64 * 2);
    uint16_t* w3l        = (uint16_t*)carve(128 * 64 * 2);

    int sbcnt = (E + CHUNK - 1) / CHUNK;   // 391 scatter blocks
    int fb = (n + 15) / 16;                // 3125 fused blocks

    // bucket cursors start at 0 (bucket-local offsets)
    hipMemsetAsync(bucket_cur, 0, 64 * 4, stream);
    // K1: edge scatter || W hi/lo split
    scatter_wprep_kernel<<<sbcnt + 160, 256, 0, stream>>>(
        ei, bucket_cur, buckets, E, sbcnt,
        W1, W2, W3, w1h, w1l, w2h, w2l, w3h, w3l);
    // K2: per-bucket CSR build (hist+scan+fill, MLP=4 batched) || gemm1
    csrfill_gemm1_kernel<<<nbuck + 782, 256, 0, stream>>>(
        buckets, bucket_cur, row_ptr, col, dinv, nbuck,
        x, w1h, w1l, y1, n);
    // K4: agg1 (src-scaled) + gemm2 -> y2 (scaled)
    agg_gemm_kernel<128, true><<<fb, 256, 0, stream>>>(
        y1, row_ptr, col, dinv, b1, w2h, w2l, y2, n);
    // K5: agg2 + gemm3 -> y3 (scaled)
    agg_gemm_kernel<64, false><<<fb, 256, 0, stream>>>(
        y2, row_ptr, col, dinv, b2, w3h, w3l, y3, n);
    // K6: final aggregate -> d_out
    agg_final_kernel<<<(n + 3) / 4, 256, 0, stream>>>(
        y3, row_ptr, col, dinv, b3, (float*)d_out, n);
}